// Round 10
// baseline (385.264 us; speedup 1.0000x reference)
//
#include <hip/hip_runtime.h>

#define LOG2E 1.44269504088896340736f

typedef __attribute__((ext_vector_type(8))) short short8;
typedef __attribute__((ext_vector_type(4))) float f32x4;
typedef __attribute__((ext_vector_type(2))) float f32x2;

constexpr int CL       = 10;              // layers per staged chunk
constexpr int LAYER_BY = 2048;            // bytes/layer: 2 tiles x 64 lanes x 16B
constexpr int CHUNK_BY = CL * LAYER_BY;   // 20480
constexpr int CHUNK_V4 = CHUNK_BY / 16;   // 1280 float4
constexpr int V4_PER_T = CHUNK_V4 / 128;  // 10 per thread (128-thread blocks)

// k-slot -> logical input position (same map in prepack/A and runtime/B, so
// the HW k-order cancels). pos 20 carries bias (B supplies 1.0); pos>20 pad=0.
__device__ __forceinline__ int slot_pos(int h, int e) {
    return (e < 4) ? (4 * h + e) : (16 + 4 * h + (e - 4));
}

__device__ __forceinline__ unsigned short f32_to_bf16_rne(float f) {
    unsigned u = __builtin_bit_cast(unsigned, f);
    unsigned r = 0x7fffu + ((u >> 16) & 1u);
    return (unsigned short)((u + r) >> 16);
}

// One block per layer; 128 threads = 2 tiles x 64 lanes. Weights/bias are
// PRE-SCALED by 0.5: acc = 0.5*z = x, feeding the Pade sigmoid directly.
__global__ void prepack(const float* __restrict__ W, const float* __restrict__ b,
                        unsigned int* __restrict__ wstream, int L)
{
    const int l    = blockIdx.x;
    const int t    = threadIdx.x >> 6;
    const int lane = threadIdx.x & 63;
    const int n    = t * 16 + (lane & 15);   // output-neuron position
    const int h    = lane >> 4;
    unsigned int words[4];
#pragma unroll
    for (int d = 0; d < 4; ++d) {
        unsigned short halves[2];
#pragma unroll
        for (int half = 0; half < 2; ++half) {
            int e   = d * 2 + half;
            int pos = slot_pos(h, e);
            float v = 0.f;
            if (n < 20) {
                if (pos < 20)       v = W[(size_t)l * 400 + n * 20 + pos];
                else if (pos == 20) v = b[(size_t)l * 20 + n];
            }
            halves[half] = f32_to_bf16_rne(v * 0.5f);
        }
        words[d] = (unsigned)halves[0] | ((unsigned)halves[1] << 16);
    }
    unsigned int* dst = wstream + ((size_t)l * LAYER_BY + t * 1024 + lane * 16) / 4;
    dst[0] = words[0]; dst[1] = words[1]; dst[2] = words[2]; dst[3] = words[3];
}

__device__ __forceinline__ unsigned cvt_pk_bf16(float lo, float hi) {
    unsigned r;
    asm("v_cvt_pk_bf16_f32 %0, %1, %2" : "=v"(r) : "v"(lo), "v"(hi));
    return r;
}

// Mask pad slots: h==0 keeps real positions 16..19; h==1 slot e=4 is pos 20
// -> constant 1.0 (bias multiplier); other upper-half slots hit zero A columns.
__device__ __forceinline__ short8 finalize_B(unsigned p0, unsigned p1,
                                             unsigned p2, unsigned p3, int h) {
    if (h != 0) { p2 = (h == 1) ? 0x00003F80u : 0u; p3 = 0u; }
    union { unsigned u[4]; short8 s; } cv;
    cv.u[0] = p0; cv.u[1] = p1; cv.u[2] = p2; cv.u[3] = p3;
    return cv.s;
}

__device__ __forceinline__ f32x2 make2(float v) { f32x2 r; r.x = v; r.y = v; return r; }

// sigmoid(z) with x = 0.5*z already in acc: sigma = 0.5 + x*Ntil(u)/D(u),
// u = x^2. abs err <= ~2e-5 for |z|<=4, <= 1.2e-3 at |z|=8. Packed f32 ops.
__device__ __forceinline__ f32x2 pade_sig(f32x2 x) {
    f32x2 u = x * x;
    f32x2 n = (u * make2(0.5f) + make2(52.5f)) * u + make2(472.5f);
    f32x2 d = (u * make2(15.0f) + make2(420.0f)) * u + make2(945.0f);
    f32x2 r;
    r.x = __builtin_amdgcn_rcpf(d.x);
    r.y = __builtin_amdgcn_rcpf(d.y);
    return (x * n) * r + make2(0.5f);
}

// full sigmoid for unscaled z (epilogue only, once)
__device__ __forceinline__ float sigm(float z) {
    return __builtin_amdgcn_rcpf(1.f + __builtin_amdgcn_exp2f(-LOG2E * z));
}

// Issue both A-fragment reads for one layer (volatile -> cannot be sunk).
__device__ __forceinline__ void issue_frag(unsigned addr, short8& t0, short8& t1) {
    asm volatile("ds_read_b128 %0, %1 offset:0"    : "=v"(t0) : "v"(addr));
    asm volatile("ds_read_b128 %0, %1 offset:1024" : "=v"(t1) : "v"(addr));
}

// One layer for TWO independent batch groups (P,Q) sharing the A fragments.
// The two chains are independent -> they fill each other's dependency stalls.
__device__ __forceinline__ void layer_step2(const short8& c0, const short8& c1,
                                            short8& BfP, short8& BfQ,
                                            f32x2 (&qP)[4], f32x2 (&qQ)[4], int h) {
    const f32x4 zero = {0.f, 0.f, 0.f, 0.f};
    f32x4 aP0 = __builtin_amdgcn_mfma_f32_16x16x32_bf16(c0, BfP, zero, 0, 0, 0);
    f32x4 aP1 = __builtin_amdgcn_mfma_f32_16x16x32_bf16(c1, BfP, zero, 0, 0, 0);
    f32x4 aQ0 = __builtin_amdgcn_mfma_f32_16x16x32_bf16(c0, BfQ, zero, 0, 0, 0);
    f32x4 aQ1 = __builtin_amdgcn_mfma_f32_16x16x32_bf16(c1, BfQ, zero, 0, 0, 0);
    qP[0].x = aP0[0]; qP[0].y = aP0[1];  qP[1].x = aP0[2]; qP[1].y = aP0[3];
    qP[2].x = aP1[0]; qP[2].y = aP1[1];  qP[3].x = aP1[2]; qP[3].y = aP1[3];
    qQ[0].x = aQ0[0]; qQ[0].y = aQ0[1];  qQ[1].x = aQ0[2]; qQ[1].y = aQ0[3];
    qQ[2].x = aQ1[0]; qQ[2].y = aQ1[1];  qQ[3].x = aQ1[2]; qQ[3].y = aQ1[3];
#pragma unroll
    for (int k = 0; k < 4; ++k) { qP[k] = pade_sig(qP[k]); qQ[k] = pade_sig(qQ[k]); }
    BfP = finalize_B(cvt_pk_bf16(qP[0].x, qP[0].y), cvt_pk_bf16(qP[1].x, qP[1].y),
                     cvt_pk_bf16(qP[2].x, qP[2].y), cvt_pk_bf16(qP[3].x, qP[3].y), h);
    BfQ = finalize_B(cvt_pk_bf16(qQ[0].x, qQ[0].y), cvt_pk_bf16(qQ[1].x, qQ[1].y),
                     cvt_pk_bf16(qQ[2].x, qQ[2].y), cvt_pk_bf16(qQ[3].x, qQ[3].y), h);
}

// 32 real batch rows per wave as TWO independent 16-row groups. 512 waves,
// 256 blocks x 128 threads (1 block/CU). A-fragments ds_read once per layer,
// shared by both groups.
__global__ __launch_bounds__(128, 1) void mann_mfma(
    const float* __restrict__ x, const unsigned int* __restrict__ wstream,
    const float* __restrict__ Wout, const float* __restrict__ bout,
    float* __restrict__ out, int B, int L)
{
    __shared__ unsigned char lds[2 * CHUNK_BY];   // 40 KiB double buffer

    const int tid  = threadIdx.x;
    const int lane = tid & 63;
    const int c16  = lane & 15;     // batch column within fragment
    const int h    = lane >> 4;     // k-group / D-row group
    const int wv   = blockIdx.x * 2 + (tid >> 6);  // wave id 0..511
    const int rowP = wv * 32 + c16;
    const int rowQ = wv * 32 + 16 + c16;

    // ---- first-layer B fragments from x ----
    const float4 xaP = *reinterpret_cast<const float4*>(x + (size_t)rowP * 20 + 4 * h);
    const float4 xbP = *reinterpret_cast<const float4*>(x + (size_t)rowP * 20 + 16);
    short8 BfP = finalize_B(cvt_pk_bf16(xaP.x, xaP.y), cvt_pk_bf16(xaP.z, xaP.w),
                            cvt_pk_bf16(xbP.x, xbP.y), cvt_pk_bf16(xbP.z, xbP.w), h);
    const float4 xaQ = *reinterpret_cast<const float4*>(x + (size_t)rowQ * 20 + 4 * h);
    const float4 xbQ = *reinterpret_cast<const float4*>(x + (size_t)rowQ * 20 + 16);
    short8 BfQ = finalize_B(cvt_pk_bf16(xaQ.x, xaQ.y), cvt_pk_bf16(xaQ.z, xaQ.w),
                            cvt_pk_bf16(xbQ.x, xbQ.y), cvt_pk_bf16(xbQ.z, xbQ.w), h);

    // ---- chunk staging: global->reg early, reg->LDS late ----
    float4 sreg[V4_PER_T];
    auto stage_load = [&](int c) {
        const float4* g = reinterpret_cast<const float4*>(wstream) + (size_t)c * CHUNK_V4;
#pragma unroll
        for (int j = 0; j < V4_PER_T; ++j) sreg[j] = g[j * 128 + tid];
    };
    auto stage_write = [&](int bufi) {
        float4* d = reinterpret_cast<float4*>(lds + bufi * CHUNK_BY);
#pragma unroll
        for (int j = 0; j < V4_PER_T; ++j) d[j * 128 + tid] = sreg[j];
    };

    const unsigned lbase = (unsigned)(uintptr_t)&lds[0];

    stage_load(0); stage_write(0); __syncthreads();

    // 4 named A-fragment buffers; buf[l & 3] holds layer l's fragments.
    short8 f0a, f0b, f1a, f1b, f2a, f2b, f3a, f3b;

    const unsigned cb0 = lbase + lane * 16;
    issue_frag(cb0,            f0a, f0b);   // layer 0
    issue_frag(cb0 + LAYER_BY, f1a, f1b);   // layer 1

    f32x2 qP[4], qQ[4];

    const int NC = L / CL;   // 100
    for (int c = 0; c < NC; ++c) {
        if (c + 1 < NC) stage_load(c + 1);           // global prefetch (vmcnt)
        const unsigned cb = lbase + (c & 1) * CHUNK_BY + lane * 16;
#pragma unroll
        for (int ll = 0; ll < CL; ++ll) {
            // Counted wait: 4 reads outstanding (ll, ll+1); drain oldest 2.
            if (ll == CL - 1) asm volatile("s_waitcnt lgkmcnt(0)");
            else              asm volatile("s_waitcnt lgkmcnt(2)");
            __builtin_amdgcn_sched_barrier(0);       // rule #18
            if (ll + 2 < CL) {
                const unsigned a = cb + (ll + 2) * LAYER_BY;
                const int bi = (ll + 2) & 3;
                if      (bi == 0) issue_frag(a, f0a, f0b);
                else if (bi == 1) issue_frag(a, f1a, f1b);
                else if (bi == 2) issue_frag(a, f2a, f2b);
                else              issue_frag(a, f3a, f3b);
            }
            __builtin_amdgcn_sched_barrier(0);
            const int ci = ll & 3;
            if      (ci == 0) layer_step2(f0a, f0b, BfP, BfQ, qP, qQ, h);
            else if (ci == 1) layer_step2(f1a, f1b, BfP, BfQ, qP, qQ, h);
            else if (ci == 2) layer_step2(f2a, f2b, BfP, BfQ, qP, qQ, h);
            else              layer_step2(f3a, f3b, BfP, BfQ, qP, qQ, h);
        }
        if (c + 1 < NC) {
            stage_write((c + 1) & 1);                // loads long since landed
            __syncthreads();
            const unsigned nb = lbase + ((c + 1) & 1) * CHUNK_BY + lane * 16;
            issue_frag(nb,            f0a, f0b);     // next chunk layer 0
            issue_frag(nb + LAYER_BY, f1a, f1b);     // next chunk layer 1
        }
    }

    // ---- epilogue: per group, lane (h,c16) holds neurons {4h+j} (q[0],q[1])
    // and {16+4h+j} (q[2],q[3]; real only for h==0) ----
    const float4 woa = *reinterpret_cast<const float4*>(Wout + 4 * h);
    const float4 wob = *reinterpret_cast<const float4*>(Wout + 16);
    const float m = (h == 0) ? 1.f : 0.f;

    float pP = qP[0].x*woa.x + qP[0].y*woa.y + qP[1].x*woa.z + qP[1].y*woa.w;
    pP += m * (qP[2].x*wob.x + qP[2].y*wob.y + qP[3].x*wob.z + qP[3].y*wob.w);
    pP += __shfl_xor(pP, 16, 64);
    pP += __shfl_xor(pP, 32, 64);

    float pQ = qQ[0].x*woa.x + qQ[0].y*woa.y + qQ[1].x*woa.z + qQ[1].y*woa.w;
    pQ += m * (qQ[2].x*wob.x + qQ[2].y*wob.y + qQ[3].x*wob.z + qQ[3].y*wob.w);
    pQ += __shfl_xor(pQ, 16, 64);
    pQ += __shfl_xor(pQ, 32, 64);

    if (h == 0) {
        out[rowP] = sigm(pP + bout[0]);
        out[rowQ] = sigm(pQ + bout[0]);
    }
}

extern "C" void kernel_launch(void* const* d_in, const int* in_sizes, int n_in,
                              void* d_out, int out_size, void* d_ws, size_t ws_size,
                              hipStream_t stream) {
    const float* x    = (const float*)d_in[0];
    const float* W    = (const float*)d_in[1];
    const float* b    = (const float*)d_in[2];
    const float* Wout = (const float*)d_in[3];
    const float* bout = (const float*)d_in[4];
    float* out = (float*)d_out;

    const int B = in_sizes[0] / 20;    // 16384
    const int L = in_sizes[1] / 400;   // 1000

    unsigned int* wstream = (unsigned int*)d_ws;   // L*2048 B = 2.05 MB

    prepack<<<L, 128, 0, stream>>>(W, b, wstream, L);

    const int grid = B / 64;           // 32 rows/wave, 2 waves/block -> 256 blocks
    mann_mfma<<<grid, 128, 0, stream>>>(x, wstream, Wout, bout, out, B, L);
}